// Round 9
// baseline (379.729 us; speedup 1.0000x reference)
//
#include <hip/hip_runtime.h>
#include <hip/hip_bf16.h>

typedef __attribute__((ext_vector_type(8))) short short8;
typedef __attribute__((ext_vector_type(4))) float f32x4;
typedef __attribute__((ext_vector_type(4))) _Float16 half4;

#define NB 4
#define NN 9216
#define NM 2304
#define NBLK (144 * NB)

__device__ inline unsigned pk2(float a, float b) {
  __hip_bfloat16 ha = __float2bfloat16(a), hb = __float2bfloat16(b);
  return (unsigned)*(unsigned short*)&ha | ((unsigned)*(unsigned short*)&hb << 16);
}
__device__ inline float ubf(unsigned u) {
  unsigned v = u << 16; return *(float*)&v;
}
__device__ inline short8 pack8(const float* v) {
  short8 s;
#pragma unroll
  for (int j = 0; j < 8; ++j) { __hip_bfloat16 h = __float2bfloat16(v[j]); s[j] = *(short*)&h; }
  return s;
}
__device__ inline short8 ldw8(const float* p) {
  float tmp[8];
  *(float4*)&tmp[0] = *(const float4*)p;
  *(float4*)&tmp[4] = *(const float4*)(p + 4);
  return pack8(tmp);
}

// Device-scope grid barrier: all 576 blocks are co-resident by construction
// (launch_bounds(256,3) -> VGPR<=168 -> 3 waves/SIMD; LDS 45.3KB -> 3 blocks/CU;
//  576 <= 3*256).  Counters zeroed by hipMemsetAsync before launch.
__device__ inline void gridbar(unsigned* c, unsigned target) {
  __syncthreads();
  __threadfence();
  if (threadIdx.x == 0) {
    atomicAdd(c, 1u);
    while (atomicAdd(c, 0u) < target) __builtin_amdgcn_s_sleep(8);
  }
  __syncthreads();
  __threadfence();
}

// ---------------------------------------------------------------------------
// Mega kernel: conv+pool -> gridbar -> attention(+residual+W-conv+BN stats)
//              -> gridbar -> BN apply (from registers).
// grid (144, NB) x 256.
// ---------------------------------------------------------------------------
__global__ __launch_bounds__(256, 3) void mega_k(
    const float* __restrict__ x, const float* __restrict__ feat,
    const float* __restrict__ tw, const float* __restrict__ tbi,
    const float* __restrict__ gw, const float* __restrict__ gbi,
    const float* __restrict__ pw, const float* __restrict__ pbi,
    const float* __restrict__ Ww, const float* __restrict__ Wb,
    const float* __restrict__ gamma, const float* __restrict__ beta,
    __hip_bfloat16* __restrict__ Theta, _Float16* __restrict__ Gcm,
    __hip_bfloat16* __restrict__ PhiT,
    unsigned* __restrict__ ctr, float* __restrict__ psum,
    float* __restrict__ out) {
  __shared__ union {
    struct { float xs[64][68]; float fs[64][36]; } cv;                         // 26624 B
    struct { __hip_bfloat16 phis[64][72]; _Float16 gs[64][72]; } st;           // 18432 B
    struct { __hip_bfloat16 zpart[4][64][68]; __hip_bfloat16 zacc[64][72]; } ep; // 44032 B
    float zt[32][68];                                                          //  8704 B
  } u;
  __shared__ float rs[4][64];
  __shared__ float ssl[64];

  int t = threadIdx.x, wv = t >> 6, lane = t & 63;
  int l15 = lane & 15, q = lane >> 4;
  int b = blockIdx.y, bx = blockIdx.x;

  // ======================= phase 0: conv1x1 + 2x2 pool =======================
  {
    int jt = bx % 3, rp = bx / 3;
    int i0 = rp * 2, j0 = jt * 32;
    int ot = wv;

#pragma unroll
    for (int p = 0; p < 4; ++p) {
      int idx = p * 256 + t;
      int c = idx >> 4, s = idx & 15;
      int row = s >> 3, cl = (s & 7) * 4;
      float4 v = *(const float4*)(x + ((size_t)b * 64 + c) * NN + (i0 + row) * 96 + j0 + cl);
      int nl = row * 32 + cl;
      u.cv.xs[nl][c] = v.x; u.cv.xs[nl + 1][c] = v.y;
      u.cv.xs[nl + 2][c] = v.z; u.cv.xs[nl + 3][c] = v.w;
    }
#pragma unroll
    for (int p = 0; p < 2; ++p) {
      int idx = p * 256 + t;
      int c = idx >> 4, s = idx & 15;
      int row = s >> 3, cl = (s & 7) * 4;
      float4 v = *(const float4*)(feat + ((size_t)b * 32 + c) * NN + (i0 + row) * 96 + j0 + cl);
      int nl = row * 32 + cl;
      u.cv.fs[nl][c] = v.x; u.cv.fs[nl + 1][c] = v.y;
      u.cv.fs[nl + 2][c] = v.z; u.cv.fs[nl + 3][c] = v.w;
    }

    short8 wt[2], wg[2], wp1;
#pragma unroll
    for (int kf = 0; kf < 2; ++kf) {
      wt[kf] = ldw8(tw + (size_t)(ot * 16 + l15) * 64 + kf * 32 + q * 8);
      wg[kf] = ldw8(gw + (size_t)(ot * 16 + l15) * 64 + kf * 32 + q * 8);
    }
    wp1 = ldw8(pw + (size_t)(ot * 16 + l15) * 32 + q * 8);

    __syncthreads();

    short8 bxf[4][2], bff[4];
    {
      float tmp[8];
#pragma unroll
      for (int tl = 0; tl < 4; ++tl) {
#pragma unroll
        for (int kf = 0; kf < 2; ++kf) {
          *(float4*)&tmp[0] = *(float4*)&u.cv.xs[tl * 16 + l15][kf * 32 + q * 8];
          *(float4*)&tmp[4] = *(float4*)&u.cv.xs[tl * 16 + l15][kf * 32 + q * 8 + 4];
          bxf[tl][kf] = pack8(tmp);
        }
        *(float4*)&tmp[0] = *(float4*)&u.cv.fs[tl * 16 + l15][q * 8];
        *(float4*)&tmp[4] = *(float4*)&u.cv.fs[tl * 16 + l15][q * 8 + 4];
        bff[tl] = pack8(tmp);
      }
    }

#pragma unroll
    for (int tl = 0; tl < 4; ++tl) {
      f32x4 d;
#pragma unroll
      for (int r = 0; r < 4; ++r) d[r] = tbi[ot * 16 + q * 4 + r];
      d = __builtin_amdgcn_mfma_f32_16x16x32_bf16(wt[0], bxf[tl][0], d, 0, 0, 0);
      d = __builtin_amdgcn_mfma_f32_16x16x32_bf16(wt[1], bxf[tl][1], d, 0, 0, 0);
      int n = (i0 + (tl >> 1)) * 96 + j0 + (tl & 1) * 16 + l15;
      size_t base = ((size_t)b * NN + n) * 64 + ot * 16 + q * 4;
      *(unsigned*)(Theta + base) = pk2(d[0], d[1]);
      *(unsigned*)(Theta + base + 2) = pk2(d[2], d[3]);
    }

    int mrow = rp * 48 + jt * 16;
    bool em = (l15 & 1) == 0;
#pragma unroll
    for (int ch = 0; ch < 2; ++ch) {
      f32x4 d0, d1;
#pragma unroll
      for (int r = 0; r < 4; ++r) { float bb = gbi[ot * 16 + q * 4 + r]; d0[r] = bb; d1[r] = bb; }
      d0 = __builtin_amdgcn_mfma_f32_16x16x32_bf16(wg[0], bxf[ch][0], d0, 0, 0, 0);
      d0 = __builtin_amdgcn_mfma_f32_16x16x32_bf16(wg[1], bxf[ch][1], d0, 0, 0, 0);
      d1 = __builtin_amdgcn_mfma_f32_16x16x32_bf16(wg[0], bxf[ch + 2][0], d1, 0, 0, 0);
      d1 = __builtin_amdgcn_mfma_f32_16x16x32_bf16(wg[1], bxf[ch + 2][1], d1, 0, 0, 0);
      float h[4];
#pragma unroll
      for (int r = 0; r < 4; ++r) {
        float v = fmaxf(d0[r], d1[r]);
        h[r] = fmaxf(v, __shfl_xor(v, 1));
      }
      if (em) {
        int m = mrow + ch * 8 + (l15 >> 1);
#pragma unroll
        for (int r = 0; r < 4; ++r)
          Gcm[((size_t)b * 64 + ot * 16 + q * 4 + r) * NM + m] = (_Float16)h[r];
      }
    }
#pragma unroll
    for (int ch = 0; ch < 2; ++ch) {
      f32x4 d0, d1;
#pragma unroll
      for (int r = 0; r < 4; ++r) { float bb = pbi[ot * 16 + q * 4 + r]; d0[r] = bb; d1[r] = bb; }
      d0 = __builtin_amdgcn_mfma_f32_16x16x32_bf16(wp1, bff[ch], d0, 0, 0, 0);
      d1 = __builtin_amdgcn_mfma_f32_16x16x32_bf16(wp1, bff[ch + 2], d1, 0, 0, 0);
      float h[4];
#pragma unroll
      for (int r = 0; r < 4; ++r) {
        float v = fmaxf(d0[r], d1[r]);
        h[r] = fmaxf(v, __shfl_xor(v, 1));
      }
      if (em) {
        int m = mrow + ch * 8 + (l15 >> 1);
        size_t base = ((size_t)b * NM + m) * 64 + ot * 16 + q * 4;
        *(unsigned*)(PhiT + base) = pk2(h[0], h[1]);
        *(unsigned*)(PhiT + base + 2) = pk2(h[2], h[3]);
      }
    }
  }

  gridbar(ctr, NBLK);

  // ======================= phase 1: attention (r8-verified) ==================
  f32x4 dd[2];
  {
    int n0 = bx * 64;

    short8 tb[4][2];
#pragma unroll
    for (int nt = 0; nt < 4; ++nt)
#pragma unroll
      for (int kf = 0; kf < 2; ++kf)
        tb[nt][kf] = *(const short8*)(Theta + ((size_t)b * NN + n0 + nt * 16 + l15) * 64 + kf * 32 + q * 8);

    f32x4 acc[4][4];
#pragma unroll
    for (int nt = 0; nt < 4; ++nt)
#pragma unroll
      for (int ct = 0; ct < 4; ++ct) acc[nt][ct] = (f32x4){0.f, 0.f, 0.f, 0.f};
    float rsum[4] = {0.f, 0.f, 0.f, 0.f};

    const __hip_bfloat16* phibase = PhiT + (size_t)b * NM * 64;
    const _Float16* gbase = Gcm + (size_t)b * 64 * NM;

    for (int ck = 0; ck < NM / 64; ++ck) {
      int m0 = ck * 64;
      __syncthreads();
#pragma unroll
      for (int p = 0; p < 2; ++p) {
        int idx = p * 256 + t, r = idx >> 3, seg = idx & 7;
        *(uint4*)&u.st.phis[r][seg * 8] = *(const uint4*)(phibase + (size_t)(m0 + r) * 64 + seg * 8);
      }
#pragma unroll
      for (int p = 0; p < 2; ++p) {
        int idx = p * 256 + t, c = idx >> 3, seg = idx & 7;
        *(uint4*)&u.st.gs[c][seg * 8] = *(const uint4*)(gbase + (size_t)c * NM + m0 + seg * 8);
      }
      __syncthreads();

      short8 pha[2];
#pragma unroll
      for (int kf = 0; kf < 2; ++kf)
        pha[kf] = *(const short8*)&u.st.phis[wv * 16 + l15][kf * 32 + q * 8];
      half4 gv[4];
#pragma unroll
      for (int ct = 0; ct < 4; ++ct)
        gv[ct] = *(const half4*)&u.st.gs[ct * 16 + l15][wv * 16 + q * 4];

      half4 pa[4];
#pragma unroll
      for (int nt = 0; nt < 4; ++nt) {
        f32x4 s = (f32x4){0.f, 0.f, 0.f, 0.f};
        s = __builtin_amdgcn_mfma_f32_16x16x32_bf16(pha[0], tb[nt][0], s, 0, 0, 0);
        s = __builtin_amdgcn_mfma_f32_16x16x32_bf16(pha[1], tb[nt][1], s, 0, 0, 0);
        float e0 = __expf(s[0]), e1 = __expf(s[1]), e2 = __expf(s[2]), e3 = __expf(s[3]);
        rsum[nt] += (e0 + e1) + (e2 + e3);
        pa[nt] = (half4){(_Float16)e0, (_Float16)e1, (_Float16)e2, (_Float16)e3};
      }
#pragma unroll
      for (int nt = 0; nt < 4; ++nt)
#pragma unroll
        for (int ct = 0; ct < 4; ++ct)
          acc[nt][ct] = __builtin_amdgcn_mfma_f32_16x16x16f16(pa[nt], gv[ct], acc[nt][ct], 0, 0, 0);
    }

#pragma unroll
    for (int nt = 0; nt < 4; ++nt) {
      float v = rsum[nt];
      v += __shfl_xor(v, 16);
      v += __shfl_xor(v, 32);
      if (lane < 16) rs[wv][nt * 16 + lane] = v;
    }
    __syncthreads();

#pragma unroll
    for (int nt = 0; nt < 4; ++nt)
#pragma unroll
      for (int ct = 0; ct < 4; ++ct)
#pragma unroll
        for (int r = 0; r < 4; ++r)
          u.ep.zpart[wv][nt * 16 + q * 4 + r][ct * 16 + l15] = __float2bfloat16(acc[nt][ct][r]);
    __syncthreads();

    {
      int row = wv * 16 + l15;
      float tot = rs[0][row] + rs[1][row] + rs[2][row] + rs[3][row];
      float rinv = 1.0f / tot;
      float ys[16];
#pragma unroll
      for (int j4 = 0; j4 < 4; ++j4) {
        uint2 p0 = *(const uint2*)&u.ep.zpart[0][row][q * 16 + j4 * 4];
        ys[j4 * 4 + 0] = ubf(p0.x & 0xffffu); ys[j4 * 4 + 1] = ubf(p0.x >> 16);
        ys[j4 * 4 + 2] = ubf(p0.y & 0xffffu); ys[j4 * 4 + 3] = ubf(p0.y >> 16);
      }
#pragma unroll
      for (int wvv = 1; wvv < 4; ++wvv) {
#pragma unroll
        for (int j4 = 0; j4 < 4; ++j4) {
          uint2 p0 = *(const uint2*)&u.ep.zpart[wvv][row][q * 16 + j4 * 4];
          ys[j4 * 4 + 0] += ubf(p0.x & 0xffffu); ys[j4 * 4 + 1] += ubf(p0.x >> 16);
          ys[j4 * 4 + 2] += ubf(p0.y & 0xffffu); ys[j4 * 4 + 3] += ubf(p0.y >> 16);
        }
      }
      float z1[16];
#pragma unroll
      for (int i = 0; i < 16; ++i)
        z1[i] = ys[i] * rinv + x[((size_t)b * 64 + q * 16 + i) * NN + n0 + row];
#pragma unroll
      for (int i2 = 0; i2 < 8; ++i2)
        *(unsigned*)&u.ep.zacc[row][q * 16 + 2 * i2] = pk2(z1[2 * i2], z1[2 * i2 + 1]);
    }
    __syncthreads();

    short8 wbf[2][2];
#pragma unroll
    for (int ot = 0; ot < 2; ++ot)
#pragma unroll
      for (int kf = 0; kf < 2; ++kf)
        wbf[ot][kf] = ldw8(Ww + (size_t)(ot * 16 + l15) * 64 + kf * 32 + q * 8);
    short8 za0 = *(const short8*)&u.ep.zacc[wv * 16 + l15][q * 8];
    short8 za1 = *(const short8*)&u.ep.zacc[wv * 16 + l15][32 + q * 8];

#pragma unroll
    for (int ot = 0; ot < 2; ++ot) {
      float bias = Wb[ot * 16 + l15];
      f32x4 d = (f32x4){bias, bias, bias, bias};
      d = __builtin_amdgcn_mfma_f32_16x16x32_bf16(za0, wbf[ot][0], d, 0, 0, 0);
      d = __builtin_amdgcn_mfma_f32_16x16x32_bf16(za1, wbf[ot][1], d, 0, 0, 0);
      dd[ot] = d;
    }

    __syncthreads();   // rs reuse for BN partials
#pragma unroll
    for (int ot = 0; ot < 2; ++ot) {
      float ps = (dd[ot][0] + dd[ot][1]) + (dd[ot][2] + dd[ot][3]);
      float ps2 = dd[ot][0] * dd[ot][0] + dd[ot][1] * dd[ot][1] +
                  dd[ot][2] * dd[ot][2] + dd[ot][3] * dd[ot][3];
      ps += __shfl_xor(ps, 16);  ps += __shfl_xor(ps, 32);
      ps2 += __shfl_xor(ps2, 16); ps2 += __shfl_xor(ps2, 32);
      if (lane < 16) {
        rs[wv][ot * 16 + lane] = ps;
        rs[wv][32 + ot * 16 + lane] = ps2;
      }
    }
    __syncthreads();
    if (t < 64) {
      float tot = rs[0][t] + rs[1][t] + rs[2][t] + rs[3][t];
      atomicAdd(&psum[t], tot);
    }
  }

  gridbar(ctr + 1, NBLK);

  // ======================= phase 2: BN finalize + apply ======================
  {
    int n0 = bx * 64;
    if (t < 32) {
      const float inv = 1.0f / (float)(NB * NN);
      float mean = psum[t] * inv;
      float var = psum[32 + t] * inv - mean * mean;
      float sc = gamma[t] * rsqrtf(var + 1e-5f);
      ssl[t] = sc;
      ssl[32 + t] = beta[t] - mean * sc;
    }
    // z2 values live in dd registers: row nw+q*4+r, channel ot*16+l15
#pragma unroll
    for (int ot = 0; ot < 2; ++ot)
#pragma unroll
      for (int r = 0; r < 4; ++r)
        u.zt[ot * 16 + l15][wv * 16 + q * 4 + r] = dd[ot][r];
    __syncthreads();

    int o = t >> 3, nseg = t & 7;
    float sc = ssl[o], sh = ssl[32 + o];
    float4 a, c;
    a.x = u.zt[o][nseg * 8 + 0] * sc + sh; a.y = u.zt[o][nseg * 8 + 1] * sc + sh;
    a.z = u.zt[o][nseg * 8 + 2] * sc + sh; a.w = u.zt[o][nseg * 8 + 3] * sc + sh;
    c.x = u.zt[o][nseg * 8 + 4] * sc + sh; c.y = u.zt[o][nseg * 8 + 5] * sc + sh;
    c.z = u.zt[o][nseg * 8 + 6] * sc + sh; c.w = u.zt[o][nseg * 8 + 7] * sc + sh;
    float* po = out + ((size_t)b * 32 + o) * NN + n0 + nseg * 8;
    *(float4*)po = a;
    *(float4*)(po + 4) = c;
  }
}

// ---------------------------------------------------------------------------
extern "C" void kernel_launch(void* const* d_in, const int* in_sizes, int n_in,
                              void* d_out, int out_size, void* d_ws, size_t ws_size,
                              hipStream_t stream) {
  const float* x       = (const float*)d_in[0];
  const float* feature = (const float*)d_in[1];
  const float* g_w     = (const float*)d_in[2];
  const float* g_b     = (const float*)d_in[3];
  const float* theta_w = (const float*)d_in[4];
  const float* theta_b = (const float*)d_in[5];
  const float* phi_w   = (const float*)d_in[6];
  const float* phi_b   = (const float*)d_in[7];
  const float* W_w     = (const float*)d_in[8];
  const float* W_b     = (const float*)d_in[9];
  const float* bn_g    = (const float*)d_in[10];
  const float* bn_b    = (const float*)d_in[11];

  char* ws = (char*)d_ws;
  __hip_bfloat16* Theta = (__hip_bfloat16*)(ws);             // 4,718,592
  _Float16*       Gcm   = (_Float16*)(ws + 4718592);         // 1,179,648
  __hip_bfloat16* PhiT  = (__hip_bfloat16*)(ws + 5898240);   // 1,179,648
  unsigned*       ctr   = (unsigned*)(ws + 7077888);         // 2 barrier counters
  float*          psum  = (float*)(ws + 7078144);            // 64 floats

  hipMemsetAsync(ws + 7077888, 0, 512, stream);
  mega_k<<<dim3(144, NB), dim3(256), 0, stream>>>(
      x, feature, theta_w, theta_b, g_w, g_b, phi_w, phi_b, W_w, W_b,
      bn_g, bn_b, Theta, Gcm, PhiT, ctr, psum, (float*)d_out);
}

// Round 10
// 142.706 us; speedup vs baseline: 2.6609x; 2.6609x over previous
//
#include <hip/hip_runtime.h>
#include <hip/hip_bf16.h>

typedef __attribute__((ext_vector_type(8))) short short8;
typedef __attribute__((ext_vector_type(4))) float f32x4;
typedef __attribute__((ext_vector_type(4))) _Float16 half4;

#define NB 4
#define NN 9216
#define NM 2304

__device__ inline unsigned pk2(float a, float b) {
  __hip_bfloat16 ha = __float2bfloat16(a), hb = __float2bfloat16(b);
  return (unsigned)*(unsigned short*)&ha | ((unsigned)*(unsigned short*)&hb << 16);
}
__device__ inline float ubf(unsigned u) {
  unsigned v = u << 16; return *(float*)&v;
}
__device__ inline short8 pack8(const float* v) {
  short8 s;
#pragma unroll
  for (int j = 0; j < 8; ++j) { __hip_bfloat16 h = __float2bfloat16(v[j]); s[j] = *(short*)&h; }
  return s;
}
__device__ inline short8 ldw8(const float* p) {
  float tmp[8];
  *(float4*)&tmp[0] = *(const float4*)p;
  *(float4*)&tmp[4] = *(const float4*)(p + 4);
  return pack8(tmp);
}

// ---------------------------------------------------------------------------
// Fused conv1x1 (theta,g,phi) + 2x2 maxpool for g/phi.  (r5/r6-verified)
// grid (288, B) x 256; wave owns one 16-wide ot slice; 1152 blocks.
// ---------------------------------------------------------------------------
__global__ __launch_bounds__(256) void conv_pool_k(
    const float* __restrict__ x, const float* __restrict__ feat,
    const float* __restrict__ tw, const float* __restrict__ tbi,
    const float* __restrict__ gw, const float* __restrict__ gbi,
    const float* __restrict__ pw, const float* __restrict__ pbi,
    __hip_bfloat16* __restrict__ Theta, _Float16* __restrict__ Gcm,
    __hip_bfloat16* __restrict__ PhiT, float* __restrict__ psum) {
  int t = threadIdx.x, wv = t >> 6, lane = t & 63, l15 = lane & 15, q = lane >> 4;
  int b = blockIdx.y, bx = blockIdx.x;
  if (bx == 0 && b == 0 && t < 64) psum[t] = 0.f;
  int jt = bx % 6, rp = bx / 6;
  int i0 = rp * 2, j0 = jt * 16;
  int ntop = i0 * 96 + j0;
  int ot = wv;

  short8 wt[2], wg[2], wp1;
#pragma unroll
  for (int kf = 0; kf < 2; ++kf) {
    wt[kf] = ldw8(tw + (size_t)(ot * 16 + l15) * 64 + kf * 32 + q * 8);
    wg[kf] = ldw8(gw + (size_t)(ot * 16 + l15) * 64 + kf * 32 + q * 8);
  }
  wp1 = ldw8(pw + (size_t)(ot * 16 + l15) * 32 + q * 8);

  short8 bxf[2][2], bff[2];
  {
    float tmp[8];
#pragma unroll
    for (int row = 0; row < 2; ++row) {
#pragma unroll
      for (int kf = 0; kf < 2; ++kf) {
#pragma unroll
        for (int j = 0; j < 8; ++j)
          tmp[j] = x[((size_t)b * 64 + kf * 32 + q * 8 + j) * NN + ntop + row * 96 + l15];
        bxf[row][kf] = pack8(tmp);
      }
#pragma unroll
      for (int j = 0; j < 8; ++j)
        tmp[j] = feat[((size_t)b * 32 + q * 8 + j) * NN + ntop + row * 96 + l15];
      bff[row] = pack8(tmp);
    }
  }

  int m = rp * 48 + ((j0 + l15) >> 1);
  bool em = (l15 & 1) == 0;

#pragma unroll
  for (int row = 0; row < 2; ++row) {
    f32x4 d;
#pragma unroll
    for (int r = 0; r < 4; ++r) d[r] = tbi[ot * 16 + q * 4 + r];
    d = __builtin_amdgcn_mfma_f32_16x16x32_bf16(wt[0], bxf[row][0], d, 0, 0, 0);
    d = __builtin_amdgcn_mfma_f32_16x16x32_bf16(wt[1], bxf[row][1], d, 0, 0, 0);
    size_t base = ((size_t)b * NN + ntop + row * 96 + l15) * 64 + ot * 16 + q * 4;
    *(unsigned*)(Theta + base) = pk2(d[0], d[1]);
    *(unsigned*)(Theta + base + 2) = pk2(d[2], d[3]);
  }
  {
    f32x4 d0, d1;
#pragma unroll
    for (int r = 0; r < 4; ++r) { float bb = gbi[ot * 16 + q * 4 + r]; d0[r] = bb; d1[r] = bb; }
    d0 = __builtin_amdgcn_mfma_f32_16x16x32_bf16(wg[0], bxf[0][0], d0, 0, 0, 0);
    d0 = __builtin_amdgcn_mfma_f32_16x16x32_bf16(wg[1], bxf[0][1], d0, 0, 0, 0);
    d1 = __builtin_amdgcn_mfma_f32_16x16x32_bf16(wg[0], bxf[1][0], d1, 0, 0, 0);
    d1 = __builtin_amdgcn_mfma_f32_16x16x32_bf16(wg[1], bxf[1][1], d1, 0, 0, 0);
    float h[4];
#pragma unroll
    for (int r = 0; r < 4; ++r) {
      float v = fmaxf(d0[r], d1[r]);
      h[r] = fmaxf(v, __shfl_xor(v, 1));
    }
    if (em) {
#pragma unroll
      for (int r = 0; r < 4; ++r)
        Gcm[((size_t)b * 64 + ot * 16 + q * 4 + r) * NM + m] = (_Float16)h[r];
    }
  }
  {
    f32x4 d0, d1;
#pragma unroll
    for (int r = 0; r < 4; ++r) { float bb = pbi[ot * 16 + q * 4 + r]; d0[r] = bb; d1[r] = bb; }
    d0 = __builtin_amdgcn_mfma_f32_16x16x32_bf16(wp1, bff[0], d0, 0, 0, 0);
    d1 = __builtin_amdgcn_mfma_f32_16x16x32_bf16(wp1, bff[1], d1, 0, 0, 0);
    float h[4];
#pragma unroll
    for (int r = 0; r < 4; ++r) {
      float v = fmaxf(d0[r], d1[r]);
      h[r] = fmaxf(v, __shfl_xor(v, 1));
    }
    if (em) {
      size_t base = ((size_t)b * NM + m) * 64 + ot * 16 + q * 4;
      *(unsigned*)(PhiT + base) = pk2(h[0], h[1]);
      *(unsigned*)(PhiT + base + 2) = pk2(h[2], h[3]);
    }
  }
}

// ---------------------------------------------------------------------------
// Fused attention (m-split waves, r8-verified) with DOUBLE-BUFFERED staging:
// one barrier per 64-m chunk; next chunk prefetched into registers and
// written to the alternate LDS buffer after compute.
// grid (144, B) x 256.
// ---------------------------------------------------------------------------
__global__ __launch_bounds__(256, 3) void attn_k(
    const __hip_bfloat16* __restrict__ Theta, const __hip_bfloat16* __restrict__ PhiT,
    const _Float16* __restrict__ Gcm, const float* __restrict__ x,
    const float* __restrict__ Ww, const float* __restrict__ Wb,
    float* __restrict__ z2, float* __restrict__ psum) {
  __shared__ union {
    struct { __hip_bfloat16 phis[2][64][72]; _Float16 gs[2][64][72]; } st;        // 36864 B
    struct { __hip_bfloat16 zpart[4][64][68]; __hip_bfloat16 zacc[64][72]; } ep;  // 44032 B
  } u;
  __shared__ float rs[4][64];

  int t = threadIdx.x, wv = t >> 6, lane = t & 63;
  int l15 = lane & 15, q = lane >> 4;
  int b = blockIdx.y;
  int n0 = blockIdx.x * 64;

  // Theta B-frags for all 4 n-tiles (held): B[k=c=kf*32+q*8+j][n=l15]
  short8 tb[4][2];
#pragma unroll
  for (int nt = 0; nt < 4; ++nt)
#pragma unroll
    for (int kf = 0; kf < 2; ++kf)
      tb[nt][kf] = *(const short8*)(Theta + ((size_t)b * NN + n0 + nt * 16 + l15) * 64 + kf * 32 + q * 8);

  f32x4 acc[4][4];
#pragma unroll
  for (int nt = 0; nt < 4; ++nt)
#pragma unroll
    for (int ct = 0; ct < 4; ++ct) acc[nt][ct] = (f32x4){0.f, 0.f, 0.f, 0.f};
  float rsum[4] = {0.f, 0.f, 0.f, 0.f};

  const __hip_bfloat16* phibase = PhiT + (size_t)b * NM * 64;
  const _Float16* gbase = Gcm + (size_t)b * 64 * NM;

  int pr = t >> 3, pseg = t & 7;   // staging decomposition (rows pr, pr+32)
  uint4 rphi[2], rg[2];

  // prologue: load + store chunk 0 into buf 0
#pragma unroll
  for (int p = 0; p < 2; ++p)
    rphi[p] = *(const uint4*)(phibase + (size_t)(p * 32 + pr) * 64 + pseg * 8);
#pragma unroll
  for (int p = 0; p < 2; ++p)
    rg[p] = *(const uint4*)(gbase + (size_t)(p * 32 + pr) * NM + pseg * 8);
#pragma unroll
  for (int p = 0; p < 2; ++p)
    *(uint4*)&u.st.phis[0][p * 32 + pr][pseg * 8] = rphi[p];
#pragma unroll
  for (int p = 0; p < 2; ++p)
    *(uint4*)&u.st.gs[0][p * 32 + pr][pseg * 8] = rg[p];

  for (int ck = 0; ck < NM / 64; ++ck) {   // 36 chunks of 64 m
    int cur = ck & 1;
    __syncthreads();   // buf[cur] writes complete; prior readers of buf[cur^1] done

    if (ck < 35) {     // prefetch chunk ck+1 (in flight during compute)
      int m1 = (ck + 1) * 64;
#pragma unroll
      for (int p = 0; p < 2; ++p)
        rphi[p] = *(const uint4*)(phibase + (size_t)(m1 + p * 32 + pr) * 64 + pseg * 8);
#pragma unroll
      for (int p = 0; p < 2; ++p)
        rg[p] = *(const uint4*)(gbase + (size_t)(p * 32 + pr) * NM + m1 + pseg * 8);
    }

    // own m-quarter frags: A[m=wv*16+l15][k=c]; G B[k=m=wv*16+q*4+j][c=l15]
    short8 pha[2];
#pragma unroll
    for (int kf = 0; kf < 2; ++kf)
      pha[kf] = *(const short8*)&u.st.phis[cur][wv * 16 + l15][kf * 32 + q * 8];
    half4 gv[4];
#pragma unroll
    for (int ct = 0; ct < 4; ++ct)
      gv[ct] = *(const half4*)&u.st.gs[cur][ct * 16 + l15][wv * 16 + q * 4];

    half4 pa[4];
#pragma unroll
    for (int nt = 0; nt < 4; ++nt) {
      // S^T quarter: D row m = wv*16+q*4+r, col n = nt*16+l15
      f32x4 s = (f32x4){0.f, 0.f, 0.f, 0.f};
      s = __builtin_amdgcn_mfma_f32_16x16x32_bf16(pha[0], tb[nt][0], s, 0, 0, 0);
      s = __builtin_amdgcn_mfma_f32_16x16x32_bf16(pha[1], tb[nt][1], s, 0, 0, 0);
      float e0 = __expf(s[0]), e1 = __expf(s[1]), e2 = __expf(s[2]), e3 = __expf(s[3]);
      rsum[nt] += (e0 + e1) + (e2 + e3);
      pa[nt] = (half4){(_Float16)e0, (_Float16)e1, (_Float16)e2, (_Float16)e3};
    }
#pragma unroll
    for (int nt = 0; nt < 4; ++nt)
#pragma unroll
      for (int ct = 0; ct < 4; ++ct)
        acc[nt][ct] = __builtin_amdgcn_mfma_f32_16x16x16f16(pa[nt], gv[ct], acc[nt][ct], 0, 0, 0);

    if (ck < 35) {     // write prefetched chunk into the other buffer
#pragma unroll
      for (int p = 0; p < 2; ++p)
        *(uint4*)&u.st.phis[cur ^ 1][p * 32 + pr][pseg * 8] = rphi[p];
#pragma unroll
      for (int p = 0; p < 2; ++p)
        *(uint4*)&u.st.gs[cur ^ 1][p * 32 + pr][pseg * 8] = rg[p];
    }
  }

  // partial rowsums (this wave's 16-m slice) -> rs[wv][n]
#pragma unroll
  for (int nt = 0; nt < 4; ++nt) {
    float v = rsum[nt];
    v += __shfl_xor(v, 16);
    v += __shfl_xor(v, 32);
    if (lane < 16) rs[wv][nt * 16 + lane] = v;
  }
  __syncthreads();   // all waves done reading staging LDS (zpart aliases it)

  // partial y -> zpart[wv][n][c]  (D: row n = q*4+r within nt, col c = ct*16+l15)
#pragma unroll
  for (int nt = 0; nt < 4; ++nt)
#pragma unroll
    for (int ct = 0; ct < 4; ++ct)
#pragma unroll
      for (int r = 0; r < 4; ++r)
        u.ep.zpart[wv][nt * 16 + q * 4 + r][ct * 16 + l15] = __float2bfloat16(acc[nt][ct][r]);
  __syncthreads();

  // combine: wave wv owns rows wv*16..+15; lane covers c = q*16..+15
  {
    int row = wv * 16 + l15;
    float tot = rs[0][row] + rs[1][row] + rs[2][row] + rs[3][row];
    float rinv = 1.0f / tot;
    float ys[16];
#pragma unroll
    for (int j4 = 0; j4 < 4; ++j4) {
      uint2 p0 = *(const uint2*)&u.ep.zpart[0][row][q * 16 + j4 * 4];
      ys[j4 * 4 + 0] = ubf(p0.x & 0xffffu); ys[j4 * 4 + 1] = ubf(p0.x >> 16);
      ys[j4 * 4 + 2] = ubf(p0.y & 0xffffu); ys[j4 * 4 + 3] = ubf(p0.y >> 16);
    }
#pragma unroll
    for (int wvv = 1; wvv < 4; ++wvv) {
#pragma unroll
      for (int j4 = 0; j4 < 4; ++j4) {
        uint2 p0 = *(const uint2*)&u.ep.zpart[wvv][row][q * 16 + j4 * 4];
        ys[j4 * 4 + 0] += ubf(p0.x & 0xffffu); ys[j4 * 4 + 1] += ubf(p0.x >> 16);
        ys[j4 * 4 + 2] += ubf(p0.y & 0xffffu); ys[j4 * 4 + 3] += ubf(p0.y >> 16);
      }
    }
    float z1[16];
#pragma unroll
    for (int i = 0; i < 16; ++i)
      z1[i] = ys[i] * rinv + x[((size_t)b * 64 + q * 16 + i) * NN + n0 + row];
#pragma unroll
    for (int i2 = 0; i2 < 8; ++i2)
      *(unsigned*)&u.ep.zacc[row][q * 16 + 2 * i2] = pk2(z1[2 * i2], z1[2 * i2 + 1]);
  }
  __syncthreads();

  // W-conv: A = zacc rows (A[n=l15][k=c]), B = Ww; rows nw = n0+wv*16
  int nw = n0 + wv * 16;
  short8 wbf[2][2];
#pragma unroll
  for (int ot = 0; ot < 2; ++ot)
#pragma unroll
    for (int kf = 0; kf < 2; ++kf)
      wbf[ot][kf] = ldw8(Ww + (size_t)(ot * 16 + l15) * 64 + kf * 32 + q * 8);
  short8 za0 = *(const short8*)&u.ep.zacc[wv * 16 + l15][q * 8];
  short8 za1 = *(const short8*)&u.ep.zacc[wv * 16 + l15][32 + q * 8];

  f32x4 dd[2];
#pragma unroll
  for (int ot = 0; ot < 2; ++ot) {
    float bias = Wb[ot * 16 + l15];
    f32x4 d = (f32x4){bias, bias, bias, bias};
    d = __builtin_amdgcn_mfma_f32_16x16x32_bf16(za0, wbf[ot][0], d, 0, 0, 0);
    d = __builtin_amdgcn_mfma_f32_16x16x32_bf16(za1, wbf[ot][1], d, 0, 0, 0);
#pragma unroll
    for (int r = 0; r < 4; ++r)
      z2[((size_t)b * NN + nw + q * 4 + r) * 32 + ot * 16 + l15] = d[r];
    dd[ot] = d;
  }

  // BN stats: block partials -> 64 global atomics (rs reused after barrier)
  __syncthreads();
#pragma unroll
  for (int ot = 0; ot < 2; ++ot) {
    float ps = (dd[ot][0] + dd[ot][1]) + (dd[ot][2] + dd[ot][3]);
    float ps2 = dd[ot][0] * dd[ot][0] + dd[ot][1] * dd[ot][1] +
                dd[ot][2] * dd[ot][2] + dd[ot][3] * dd[ot][3];
    ps += __shfl_xor(ps, 16);  ps += __shfl_xor(ps, 32);
    ps2 += __shfl_xor(ps2, 16); ps2 += __shfl_xor(ps2, 32);
    if (lane < 16) {
      rs[wv][ot * 16 + lane] = ps;
      rs[wv][32 + ot * 16 + lane] = ps2;
    }
  }
  __syncthreads();
  if (t < 64) {
    float tot = rs[0][t] + rs[1][t] + rs[2][t] + rs[3][t];
    atomicAdd(&psum[t], tot);
  }
}

// ---------------------------------------------------------------------------
// BN finalize + apply + transpose [n][32] -> [32][n].
// ---------------------------------------------------------------------------
__global__ __launch_bounds__(256) void bn_apply(
    const float* __restrict__ z2, const float* __restrict__ psum,
    const float* __restrict__ gamma, const float* __restrict__ beta,
    float* __restrict__ out) {
  __shared__ float ssl[64];
  __shared__ float zt[32][65];
  int t = threadIdx.x, b = blockIdx.y, n0 = blockIdx.x * 64;
  if (t < 32) {
    const float inv = 1.0f / (float)(NB * NN);
    float mean = psum[t] * inv;
    float var = psum[32 + t] * inv - mean * mean;
    float sc = gamma[t] * rsqrtf(var + 1e-5f);
    ssl[t] = sc;
    ssl[32 + t] = beta[t] - mean * sc;
  }
#pragma unroll
  for (int it = 0; it < 2; ++it) {
    int idx = it * 256 + t, r = idx >> 3, seg = idx & 7;
    float4 vv = *(const float4*)(z2 + ((size_t)b * NN + n0 + r) * 32 + seg * 4);
    zt[seg * 4 + 0][r] = vv.x; zt[seg * 4 + 1][r] = vv.y;
    zt[seg * 4 + 2][r] = vv.z; zt[seg * 4 + 3][r] = vv.w;
  }
  __syncthreads();
  int o = t >> 3, nseg = t & 7;
  float sc = ssl[o], sh = ssl[32 + o];
  float4 a, c;
  a.x = zt[o][nseg * 8 + 0] * sc + sh; a.y = zt[o][nseg * 8 + 1] * sc + sh;
  a.z = zt[o][nseg * 8 + 2] * sc + sh; a.w = zt[o][nseg * 8 + 3] * sc + sh;
  c.x = zt[o][nseg * 8 + 4] * sc + sh; c.y = zt[o][nseg * 8 + 5] * sc + sh;
  c.z = zt[o][nseg * 8 + 6] * sc + sh; c.w = zt[o][nseg * 8 + 7] * sc + sh;
  float* po = out + ((size_t)b * 32 + o) * NN + n0 + nseg * 8;
  *(float4*)po = a;
  *(float4*)(po + 4) = c;
}

// ---------------------------------------------------------------------------
extern "C" void kernel_launch(void* const* d_in, const int* in_sizes, int n_in,
                              void* d_out, int out_size, void* d_ws, size_t ws_size,
                              hipStream_t stream) {
  const float* x       = (const float*)d_in[0];
  const float* feature = (const float*)d_in[1];
  const float* g_w     = (const float*)d_in[2];
  const float* g_b     = (const float*)d_in[3];
  const float* theta_w = (const float*)d_in[4];
  const float* theta_b = (const float*)d_in[5];
  const float* phi_w   = (const float*)d_in[6];
  const float* phi_b   = (const float*)d_in[7];
  const float* W_w     = (const float*)d_in[8];
  const float* W_b     = (const float*)d_in[9];
  const float* bn_g    = (const float*)d_in[10];
  const float* bn_b    = (const float*)d_in[11];

  char* ws = (char*)d_ws;
  __hip_bfloat16* Theta = (__hip_bfloat16*)(ws);             // 4,718,592
  _Float16*       Gcm   = (_Float16*)(ws + 4718592);         // 1,179,648
  __hip_bfloat16* PhiT  = (__hip_bfloat16*)(ws + 5898240);   // 1,179,648
  float*          z2    = (float*)(ws + 7077888);            // 4,718,592
  float*          psum  = (float*)(ws + 11796480);           // 256

  conv_pool_k<<<dim3(288, NB), dim3(256), 0, stream>>>(
      x, feature, theta_w, theta_b, g_w, g_b, phi_w, phi_b, Theta, Gcm, PhiT, psum);
  attn_k<<<dim3(144, NB), dim3(256), 0, stream>>>(
      Theta, PhiT, Gcm, x, W_w, W_b, z2, psum);
  bn_apply<<<dim3(144, NB), dim3(256), 0, stream>>>(
      z2, psum, bn_g, bn_b, (float*)d_out);
}